// Round 14
// baseline (231.849 us; speedup 1.0000x reference)
//
#include <hip/hip_runtime.h>

// exp-fold: p = exp(z*0.125 + qh + qw) computed as exp2(z*SCALE2 + qh2 + qw2)
// where the rel tables (hence qh/qw) are pre-scaled by log2(e) in the
// prologue and SCALE2 = 0.125 * log2(e). Deletes the v_mul_f32 that __expf
// puts on the serial softmax chain (32/lane/iter in a latency-bound kernel).
#define SCALE2 0.18033688011112042f
#define LOG2E  1.4426950408889634f

typedef short short8 __attribute__((ext_vector_type(8)));
typedef float f32x4 __attribute__((ext_vector_type(4)));
typedef unsigned short us8 __attribute__((ext_vector_type(8)));

__device__ __forceinline__ unsigned short f2bf(float x) {
  unsigned int u = __float_as_uint(x);
  u += 0x7fff + ((u >> 16) & 1);
  return (unsigned short)(u >> 16);
}
__device__ __forceinline__ float bf2f(unsigned short b) {
  return __uint_as_float(((unsigned int)b) << 16);
}
__device__ __forceinline__ float gelu_exact(float x) {
  return 0.5f * x * (1.0f + erff(x * 0.70710678118654752f));
}
// async global -> LDS DMA, 16 B per lane; lds base must be wave-uniform,
// lane i lands at lds + i*16. Tracked by vmcnt (drained by __syncthreads).
__device__ __forceinline__ void gl2lds16(const unsigned short* g, unsigned short* l) {
  __builtin_amdgcn_global_load_lds(
      (const __attribute__((address_space(1))) unsigned int*)g,
      (__attribute__((address_space(3))) unsigned int*)l, 16, 0, 0);
}

// ---------------------------------------------------------------------------
// Fused preprocessing: one launch, range-branched.
//   bid <  1152           : cast_w  (qkvf|qkvp|fc1w|fc2w -> wc bf16)
//   bid <  1152+1024      : trans_x (x -> xT transposed bf16)
//   else (256 blocks)     : trans_gb(gamma/beta -> gbT transposed bf16)
// ---------------------------------------------------------------------------
__global__ __launch_bounds__(256)
void prep_k(const float* __restrict__ qf, const float* __restrict__ qp,
            const float* __restrict__ f1, const float* __restrict__ f2,
            unsigned short* __restrict__ wc,
            const float* __restrict__ x, unsigned short* __restrict__ xT,
            const float* __restrict__ gamma, const float* __restrict__ beta,
            unsigned short* __restrict__ gbT)
{
  __shared__ unsigned short L[64 * 72];
  const int bid = blockIdx.x;
  if (bid < 1152) {
    const int i4 = (bid * 256 + threadIdx.x) * 4;   // 1179648 total elems
    const float* src; int off;
    if (i4 < 196608)      { src = qf; off = i4; }
    else if (i4 < 393216) { src = qp; off = i4 - 196608; }
    else if (i4 < 917504) { src = f1; off = i4 - 393216; }
    else                  { src = f2; off = i4 - 917504; }
    const float4 v = *(const float4*)(src + off);
    ushort4 o;
    o.x = f2bf(v.x); o.y = f2bf(v.y); o.z = f2bf(v.z); o.w = f2bf(v.w);
    *(ushort4*)(wc + i4) = o;
    return;
  }
  if (bid < 1152 + 1024) {
    const int idx = bid - 1152;                     // (4,16,16) flattened
    const int ch0 = (idx & 3) * 64, tok0 = ((idx >> 2) & 15) * 64, z = idx >> 6;
    const int b = z & 7, path = z >> 3;
    const float* src = x + (size_t)b * 524288 + (size_t)(path * 256 + ch0) * 1024 + tok0;
#pragma unroll
    for (int t = 0; t < 4; ++t) {
      const int i = threadIdx.x + t * 256;
      const int row = i >> 4, c4 = (i & 15) * 4;    // row = ch, c4 = tok
      const float4 v = *(const float4*)(src + (size_t)row * 1024 + c4);
      L[(c4 + 0) * 72 + row] = f2bf(v.x);
      L[(c4 + 1) * 72 + row] = f2bf(v.y);
      L[(c4 + 2) * 72 + row] = f2bf(v.z);
      L[(c4 + 3) * 72 + row] = f2bf(v.w);
    }
    __syncthreads();
    unsigned short* dst = xT + (size_t)z * 262144 + (size_t)tok0 * 256 + ch0;
#pragma unroll
    for (int t = 0; t < 2; ++t) {
      const int i = threadIdx.x + t * 256;
      const int row = i >> 3, c8 = (i & 7) * 8;     // row = tok, c8 = ch
      *(us8*)(dst + (size_t)row * 256 + c8) = *(const us8*)&L[row * 72 + c8];
    }
    return;
  }
  {
    const int idx = bid - 2176;                     // (8,16,2) flattened
    const int ch0 = (idx & 7) * 64, tok0 = ((idx >> 3) & 15) * 64, which = idx >> 7;
    const float* src = (which ? beta : gamma) + (size_t)ch0 * 1024 + tok0;
#pragma unroll
    for (int t = 0; t < 4; ++t) {
      const int i = threadIdx.x + t * 256;
      const int row = i >> 4, c4 = (i & 15) * 4;
      const float4 v = *(const float4*)(src + (size_t)row * 1024 + c4);
      L[(c4 + 0) * 72 + row] = f2bf(v.x);
      L[(c4 + 1) * 72 + row] = f2bf(v.y);
      L[(c4 + 2) * 72 + row] = f2bf(v.z);
      L[(c4 + 3) * 72 + row] = f2bf(v.w);
    }
    __syncthreads();
    unsigned short* dst = gbT + (size_t)which * 524288 + (size_t)tok0 * 512 + ch0;
#pragma unroll
    for (int t = 0; t < 2; ++t) {
      const int i = threadIdx.x + t * 256;
      const int row = i >> 3, c8 = (i & 7) * 8;
      *(us8*)(dst + (size_t)row * 512 + c8) = *(const us8*)&L[row * 72 + c8];
    }
  }
}

// ---------------------------------------------------------------------------
// MFMA GEMM v6 (R13-proven): C[M][N] = A[M][K] @ B[N][K]^T, bf16.
// BM x 64 block tile, 4 waves (2x2), BK=64 K-steps. global_load_lds DMA
// staging (T3 ordering, pre-XOR'd source swizzle q^(row&7), 1 barrier/step).
// LDS-transpose epilogues (R12-proven, -12.7us): coalesced 16B stores.
// MODE 0: qkv -> qkT[z][tok][512] (m<512, transposed) + vbuf[z][ch][tok]
// MODE 1: fc1 -> bias+gelu -> hT[z][tok][1024] bf16 (transposed)
// MODE 2: fc2 -> bias -> out[z][oc][tok] f32
// ---------------------------------------------------------------------------
template<int MODE, int K, int BM>
__global__ __launch_bounds__(256, 3)
void gemm_mf(const unsigned short* __restrict__ A0, const unsigned short* __restrict__ B0,
             unsigned short* __restrict__ qkT, unsigned short* __restrict__ vb,
             unsigned short* __restrict__ hT, float* __restrict__ outF,
             const float* __restrict__ bias)
{
  constexpr int BN = 64;
  constexpr int MI = BM / 32;                 // fragments per wave in M
  constexpr int NI = BN / 32;                 // = 2
  constexpr int ABUF = BM * 64;               // shorts per A buffer
  constexpr int BBUF = BN * 64;               // shorts per B buffer
  constexpr int STG_A = 2 * ABUF;
  constexpr int STG = STG_A + 2 * BBUF;
  constexpr int USZ = (STG > 9216) ? STG : 9216;  // epilogue needs <= 9216
  __shared__ __align__(16) unsigned short U[USZ];
  const int tid = threadIdx.x;
  const int lane = tid & 63, w = tid >> 6;
  const int c = lane & 15, g = lane >> 4;
  const int wm = w >> 1, wn = w & 1;
  const int m0 = blockIdx.x * BM, n0 = blockIdx.y * BN;
  const int z = blockIdx.z;

  const unsigned short* A;
  const unsigned short* B;
  if (MODE == 0) {
    A = A0 + (size_t)(z >> 3) * 196608;
    B = B0 + (size_t)z * 262144;
  } else {
    A = A0;
    B = B0 + (size_t)z * 1024 * K;
  }

  f32x4 acc[MI][NI];
#pragma unroll
  for (int mi = 0; mi < MI; ++mi)
#pragma unroll
    for (int ni = 0; ni < NI; ++ni) acc[mi][ni] = (f32x4){0.f, 0.f, 0.f, 0.f};

  // DMA geometry (BK=64): rows are 64 shorts = 8 chunks of 8. One call
  // covers 8 rows (64 lanes x 8 shorts). Lane l -> row = base + (l>>3),
  // chunk q = l&7, source chunk pre-XOR'd (q ^ (row&7)); (row&7) is
  // invariant under the +8 call stride, so one sc8 serves all calls.
  const int r0a = (BM == 128) ? (w * 32 + (lane >> 3)) : (w * 16 + (lane >> 3));
  const int sc8a = ((lane & 7) ^ (r0a & 7)) * 8;
  const int loa = (BM == 128) ? (w * 2048) : (w * 1024);
  const int r0b = w * 16 + (lane >> 3);       // B: 64 rows, 2 calls/wave
  const int sc8b = ((lane & 7) ^ (r0b & 7)) * 8;
  const int lob = w * 1024;

  // prologue: DMA tile 0 into buf 0
  gl2lds16(A + (size_t)(m0 + r0a) * K + sc8a,      &U[loa]);
  gl2lds16(A + (size_t)(m0 + r0a + 8) * K + sc8a,  &U[loa + 512]);
  if (BM == 128) {
    gl2lds16(A + (size_t)(m0 + r0a + 16) * K + sc8a, &U[loa + 1024]);
    gl2lds16(A + (size_t)(m0 + r0a + 24) * K + sc8a, &U[loa + 1536]);
  }
  gl2lds16(B + (size_t)(n0 + r0b) * K + sc8b,      &U[STG_A + lob]);
  gl2lds16(B + (size_t)(n0 + r0b + 8) * K + sc8b,  &U[STG_A + lob + 512]);
  __syncthreads();   // drain tile-0 DMA

  const int NK = K / 64;
  for (int ks = 0; ks < NK; ++ks) {
    const int buf = ks & 1;
    if (ks + 1 < NK) {
      const int k0 = (ks + 1) * 64;
      const int nb = buf ^ 1;
      gl2lds16(A + (size_t)(m0 + r0a) * K + k0 + sc8a,      &U[nb * ABUF + loa]);
      gl2lds16(A + (size_t)(m0 + r0a + 8) * K + k0 + sc8a,  &U[nb * ABUF + loa + 512]);
      if (BM == 128) {
        gl2lds16(A + (size_t)(m0 + r0a + 16) * K + k0 + sc8a, &U[nb * ABUF + loa + 1024]);
        gl2lds16(A + (size_t)(m0 + r0a + 24) * K + k0 + sc8a, &U[nb * ABUF + loa + 1536]);
      }
      gl2lds16(B + (size_t)(n0 + r0b) * K + k0 + sc8b,      &U[STG_A + nb * BBUF + lob]);
      gl2lds16(B + (size_t)(n0 + r0b + 8) * K + k0 + sc8b,  &U[STG_A + nb * BBUF + lob + 512]);
    }
    // fragments: k-half h chunk = 4h+g, stored at chunk (4h+g)^(row&7)
    short8 aF[MI][2], bF[NI][2];
#pragma unroll
    for (int mi = 0; mi < MI; ++mi) {
      const int row = (BM / 2) * wm + 16 * mi + c;
      const int base = buf * ABUF + row * 64;
      aF[mi][0] = *(const short8*)&U[base + ((g ^ (row & 7)) * 8)];
      aF[mi][1] = *(const short8*)&U[base + (((4 + g) ^ (row & 7)) * 8)];
    }
#pragma unroll
    for (int ni = 0; ni < NI; ++ni) {
      const int row = 32 * wn + 16 * ni + c;
      const int base = STG_A + buf * BBUF + row * 64;
      bF[ni][0] = *(const short8*)&U[base + ((g ^ (row & 7)) * 8)];
      bF[ni][1] = *(const short8*)&U[base + (((4 + g) ^ (row & 7)) * 8)];
    }
#pragma unroll
    for (int mi = 0; mi < MI; ++mi)
#pragma unroll
      for (int ni = 0; ni < NI; ++ni) {
        acc[mi][ni] = __builtin_amdgcn_mfma_f32_16x16x32_bf16(aF[mi][0], bF[ni][0], acc[mi][ni], 0, 0, 0);
        acc[mi][ni] = __builtin_amdgcn_mfma_f32_16x16x32_bf16(aF[mi][1], bF[ni][1], acc[mi][ni], 0, 0, 0);
      }
    // single end-of-iteration barrier: vmcnt(0) drain lands after the full
    // compute phase, so the tile-(ks+1) DMA latency is hidden.
    __syncthreads();
  }
  // (final barrier above also makes U safe to reuse for the epilogue)

  if (MODE == 0) {
    if (m0 < 512) {
      // qkT[z][n][512]: LDS tile [64 n][BM mb], row stride 136; single pass.
#pragma unroll
      for (int mi = 0; mi < MI; ++mi)
#pragma unroll
        for (int ni = 0; ni < NI; ++ni) {
          const int row = 32 * wn + 16 * ni + c;
          const int col = (BM / 2) * wm + 16 * mi + 4 * g;
          ushort4 o4;
          o4.x = f2bf(acc[mi][ni][0]); o4.y = f2bf(acc[mi][ni][1]);
          o4.z = f2bf(acc[mi][ni][2]); o4.w = f2bf(acc[mi][ni][3]);
          *(ushort4*)&U[row * 136 + col] = o4;
        }
      __syncthreads();
#pragma unroll
      for (int t = 0; t < 4; ++t) {
        const int i = tid + t * 256;
        const int row = i >> 4, c8 = (i & 15) * 8;
        *(us8*)(qkT + (size_t)z * 524288 + (size_t)(n0 + row) * 512 + m0 + c8)
            = *(const us8*)&U[row * 136 + c8];
      }
    } else {
      // vbuf[z][ch][1024]: LDS tile [BM ch][64 n], row stride 72; single pass.
#pragma unroll
      for (int mi = 0; mi < MI; ++mi)
#pragma unroll
        for (int ni = 0; ni < NI; ++ni) {
          const int mbl = (BM / 2) * wm + 16 * mi + 4 * g;
          const int nl = 32 * wn + 16 * ni + c;
#pragma unroll
          for (int r = 0; r < 4; ++r)
            U[(mbl + r) * 72 + nl] = f2bf(acc[mi][ni][r]);
        }
      __syncthreads();
#pragma unroll
      for (int t = 0; t < 4; ++t) {
        const int i = tid + t * 256;
        const int row = i >> 3, c8 = (i & 7) * 8;
        *(us8*)(vb + (size_t)z * 262144 + (size_t)(m0 - 512 + row) * 1024 + n0 + c8)
            = *(const us8*)&U[row * 72 + c8];
      }
    }
  } else if (MODE == 1) {
    // hT[z][tok][1024]: LDS tile [64 n][BM mb], row stride 136; single pass.
#pragma unroll
    for (int mi = 0; mi < MI; ++mi) {
      const int mb = m0 + (BM / 2) * wm + 16 * mi + 4 * g;
      const float4 b4 = *(const float4*)(bias + mb);
#pragma unroll
      for (int ni = 0; ni < NI; ++ni) {
        const int row = 32 * wn + 16 * ni + c;
        const int col = (BM / 2) * wm + 16 * mi + 4 * g;
        ushort4 o4;
        o4.x = f2bf(gelu_exact(acc[mi][ni][0] + b4.x));
        o4.y = f2bf(gelu_exact(acc[mi][ni][1] + b4.y));
        o4.z = f2bf(gelu_exact(acc[mi][ni][2] + b4.z));
        o4.w = f2bf(gelu_exact(acc[mi][ni][3] + b4.w));
        *(ushort4*)&U[row * 136 + col] = o4;
      }
    }
    __syncthreads();
#pragma unroll
    for (int t = 0; t < 4; ++t) {
      const int i = tid + t * 256;
      const int row = i >> 4, c8 = (i & 15) * 8;
      *(us8*)(hT + (size_t)z * 1048576 + (size_t)(n0 + row) * 1024 + m0 + c8)
          = *(const us8*)&U[row * 136 + c8];
    }
  } else {
    // out[z][oc][1024] f32: LDS tile [BM=64 oc][64 n] f32, stride 68; 1 pass.
    float* Uf = (float*)U;
#pragma unroll
    for (int mi = 0; mi < MI; ++mi) {
      const int mb = m0 + (BM / 2) * wm + 16 * mi + 4 * g;
      const float4 b4 = *(const float4*)(bias + mb);
#pragma unroll
      for (int ni = 0; ni < NI; ++ni) {
        const int mbl = (BM / 2) * wm + 16 * mi + 4 * g;
        const int nl = 32 * wn + 16 * ni + c;
        Uf[(mbl + 0) * 68 + nl] = acc[mi][ni][0] + b4.x;
        Uf[(mbl + 1) * 68 + nl] = acc[mi][ni][1] + b4.y;
        Uf[(mbl + 2) * 68 + nl] = acc[mi][ni][2] + b4.z;
        Uf[(mbl + 3) * 68 + nl] = acc[mi][ni][3] + b4.w;
      }
    }
    __syncthreads();
#pragma unroll
    for (int t = 0; t < 4; ++t) {
      const int i = tid + t * 256;
      const int row = i >> 4, c4 = (i & 15) * 4;
      *(float4*)(outF + (size_t)z * 262144 + (size_t)(m0 + row) * 1024 + n0 + c4)
          = *(const float4*)&Uf[row * 68 + c4];
    }
  }
}

// ---------------------------------------------------------------------------
// MFMA flash attention v11: v3 structure (FROZEN) + exp2 fold.
// The ONLY change vs the R13 kernel: rel tables pre-scaled by log2(e) in the
// prologue (qh/qw emerge pre-scaled from the MFMA) and the softmax uses
// exp2f(fmaf(z, SCALE2, qh+qw)) — removing the v_mul_f32 that __expf placed
// on the serial chain (32/lane/iter). Structure untouched: six structural
// probes (occupancy v5/v9, DMA v6, P-in-reg v8, barrier-free v10) all
// regressed or were neutral.
// ---------------------------------------------------------------------------
__global__ __launch_bounds__(256, 2)
void attn_k(const unsigned short* __restrict__ qkT,  // [16][1024][512] bf16
            const unsigned short* __restrict__ vbuf, // [16][256][1024] bf16
            const float* __restrict__ hrel,          // [63][64] f32
            const float* __restrict__ wrel,          // [63][64] f32
            unsigned short* __restrict__ xpfT,       // [8][1024][512] bf16
            float* __restrict__ stats)               // [8][2] f32
{
  __shared__ unsigned short Kb[2][4096];   // K tile [key][d], swizzled
  __shared__ unsigned short Vb[2][4096];   // V tile [d][key], swizzled
  __shared__ unsigned short Ps[128 * 72];  // QW table / P tile / Out stage
  __shared__ unsigned short QHt[128 * 34]; // qh[row][h2], h2 in [0,32)

  const int tid = threadIdx.x;
  const int lane = tid & 63, w = tid >> 6;
  const int c = lane & 15, g = lane >> 4;
  const int xb = blockIdx.x;
  const int pOut = xb >> 5, bh = xb & 31;
  const int b = bh >> 2, head = bh & 3, pKV = 1 - pOut;
  const int n0 = blockIdx.y * 128;
  const int rb = 32 * w;

  const unsigned short* Qg = qkT + (size_t)(pOut * 8 + b) * 524288 + head * 64;
  const unsigned short* Kg = qkT + (size_t)(pKV * 8 + b) * 524288 + 256 + head * 64;
  const unsigned short* Vg = vbuf + ((size_t)(pKV * 8 + b) * 256 + head * 64) * 1024;

  // ---- issue tile-0 staging loads first (latency hidden behind prologue)
  us8 kr[2], vr[2];
#pragma unroll
  for (int t = 0; t < 2; ++t) {
    const int i = tid + t * 256;
    const int row = i >> 3, ch = i & 7;
    kr[t] = *(const us8*)(Kg + (size_t)row * 512 + ch * 8);
    vr[t] = *(const us8*)(Vg + (size_t)row * 1024 + ch * 8);
  }

  // ---- Q B-fragments for the wave's 2 row-groups (resident all kernel)
  short8 bQ[2][2];
#pragma unroll
  for (int grp = 0; grp < 2; ++grp) {
    const unsigned short* qp = Qg + (size_t)(n0 + rb + 16 * grp + c) * 512 + 8 * g;
    bQ[grp][0] = *(const short8*)(qp);
    bQ[grp][1] = *(const short8*)(qp + 32);
  }

  // ---- prologue: QW/QH via MFMA (A=rel rows * log2e, B=Q).
#pragma unroll
  for (int f = 0; f < 4; ++f) {
    const int rr = 16 * f + c;
    const int rrc = rr < 63 ? rr : 62;
    const float sc = rr < 63 ? LOG2E : 0.f;     // fold log2(e) into qh/qw
    short8 w0, w1, h0, h1;
#pragma unroll
    for (int j = 0; j < 8; ++j) {
      w0[j] = f2bf(wrel[rrc * 64 + 8 * g + j] * sc);
      w1[j] = f2bf(wrel[rrc * 64 + 32 + 8 * g + j] * sc);
      h0[j] = f2bf(hrel[rrc * 64 + 8 * g + j] * sc);
      h1[j] = f2bf(hrel[rrc * 64 + 32 + 8 * g + j] * sc);
    }
#pragma unroll
    for (int grp = 0; grp < 2; ++grp) {
      f32x4 zw = {0.f, 0.f, 0.f, 0.f};
      zw = __builtin_amdgcn_mfma_f32_16x16x32_bf16(w0, bQ[grp][0], zw, 0, 0, 0);
      zw = __builtin_amdgcn_mfma_f32_16x16x32_bf16(w1, bQ[grp][1], zw, 0, 0, 0);
      f32x4 zh = {0.f, 0.f, 0.f, 0.f};
      zh = __builtin_amdgcn_mfma_f32_16x16x32_bf16(h0, bQ[grp][0], zh, 0, 0, 0);
      zh = __builtin_amdgcn_mfma_f32_16x16x32_bf16(h1, bQ[grp][1], zh, 0, 0, 0);
      const int qrow = rb + 16 * grp + c;          // lane's own q-row
      ushort4 pw;
      pw.x = f2bf(zw[0]); pw.y = f2bf(zw[1]); pw.z = f2bf(zw[2]); pw.w = f2bf(zw[3]);
      *(ushort4*)&Ps[qrow * 72 + 16 * f + 4 * g] = pw;   // QW[qrow][rw]
      const int h1i = (n0 + qrow) >> 5;
#pragma unroll
      for (int r = 0; r < 4; ++r) {
        const int h2 = 16 * f + 4 * g + r - 31 + h1i;
        if (h2 >= 0 && h2 < 32) QHt[qrow * 34 + h2] = f2bf(zh[r]);
      }
    }
  }

  // read back the 16 loop-invariant qw values (wave-private rows, in-order LDS)
  float qwv[2][2][4];
#pragma unroll
  for (int grp = 0; grp < 2; ++grp) {
    const int qrow = rb + 16 * grp + c;
    const int w1i = (n0 + qrow) & 31;
#pragma unroll
    for (int p = 0; p < 2; ++p)
#pragma unroll
      for (int r = 0; r < 4; ++r)
        qwv[grp][p][r] = bf2f(Ps[qrow * 72 + (16 * p + 4 * g + r - w1i + 31)]);
  }

  // write tile 0 to buffer 0
#pragma unroll
  for (int t = 0; t < 2; ++t) {
    const int i = tid + t * 256;
    const int row = i >> 3, ch = i & 7;
    const int p = row * 64 + ((ch ^ (row & 7)) * 8);
    *(us8*)&Kb[0][p] = kr[t];
    *(us8*)&Vb[0][p] = vr[t];
  }

  float lsum[2] = {0.f, 0.f};
  f32x4 O[2][4];
#pragma unroll
  for (int grp = 0; grp < 2; ++grp)
#pragma unroll
    for (int f = 0; f < 4; ++f) O[grp][f] = (f32x4){0.f, 0.f, 0.f, 0.f};

  for (int mt = 0; mt < 16; ++mt) {
    if (mt < 15) {
      const int m0n = (mt + 1) * 64;
#pragma unroll
      for (int t = 0; t < 2; ++t) {
        const int i = tid + t * 256;
        const int row = i >> 3, ch = i & 7;
        kr[t] = *(const us8*)(Kg + (size_t)(m0n + row) * 512 + ch * 8);
        vr[t] = *(const us8*)(Vg + (size_t)row * 1024 + m0n + ch * 8);
      }
    }
    __syncthreads();   // current buffer staged & all prior-tile reads done
    const unsigned short* Ks = Kb[mt & 1];
    const unsigned short* Vs = Vb[mt & 1];

    // K fragments (shared by both q-groups)
    short8 kA[4][2];
#pragma unroll
    for (int f = 0; f < 4; ++f) {
      const int row = 16 * f + c;
      kA[f][0] = *(const short8*)&Ks[row * 64 + ((g ^ (row & 7)) * 8)];
      kA[f][1] = *(const short8*)&Ks[row * 64 + (((4 + g) ^ (row & 7)) * 8)];
    }
    // S^T = K Q^T, softmax via exp2 (pre-scaled qh/qw), P -> LDS
#pragma unroll
    for (int grp = 0; grp < 2; ++grp) {
      const int qrow = rb + 16 * grp + c;
      const float qh0 = bf2f(QHt[qrow * 34 + 2 * mt]);
      const float qh1 = bf2f(QHt[qrow * 34 + 2 * mt + 1]);
#pragma unroll
      for (int f = 0; f < 4; ++f) {
        f32x4 z = {0.f, 0.f, 0.f, 0.f};
        z = __builtin_amdgcn_mfma_f32_16x16x32_bf16(kA[f][0], bQ[grp][0], z, 0, 0, 0);
        z = __builtin_amdgcn_mfma_f32_16x16x32_bf16(kA[f][1], bQ[grp][1], z, 0, 0, 0);
        const float qh = (f >= 2) ? qh1 : qh0;
        const float* qwp = qwv[grp][f & 1];
        const float p0 = exp2f(fmaf(z[0], SCALE2, qh + qwp[0]));
        const float p1 = exp2f(fmaf(z[1], SCALE2, qh + qwp[1]));
        const float p2 = exp2f(fmaf(z[2], SCALE2, qh + qwp[2]));
        const float p3 = exp2f(fmaf(z[3], SCALE2, qh + qwp[3]));
        lsum[grp] += (p0 + p1) + (p2 + p3);
        ushort4 pk;
        pk.x = f2bf(p0); pk.y = f2bf(p1); pk.z = f2bf(p2); pk.w = f2bf(p3);
        *(ushort4*)&Ps[qrow * 72 + 16 * f + 4 * g] = pk;
      }
    }
    // V fragments (shared by both q-groups)
    short8 vB[4][2];
#pragma unroll
    for (int f = 0; f < 4; ++f) {
      const int row = 16 * f + c;
      vB[f][0] = *(const short8*)&Vs[row * 64 + ((g ^ (row & 7)) * 8)];
      vB[f][1] = *(const short8*)&Vs[row * 64 + (((4 + g) ^ (row & 7)) * 8)];
    }
    // O += P V  (A=P from wave-private LDS rows, in-wave ordering)
#pragma unroll
    for (int grp = 0; grp < 2; ++grp) {
      const int qrow = rb + 16 * grp + c;
      const short8 aP0 = *(const short8*)&Ps[qrow * 72 + 8 * g];
      const short8 aP1 = *(const short8*)&Ps[qrow * 72 + 32 + 8 * g];
#pragma unroll
      for (int f = 0; f < 4; ++f) {
        O[grp][f] = __builtin_amdgcn_mfma_f32_16x16x32_bf16(aP0, vB[f][0], O[grp][f], 0, 0, 0);
        O[grp][f] = __builtin_amdgcn_mfma_f32_16x16x32_bf16(aP1, vB[f][1], O[grp][f], 0, 0, 0);
      }
    }
    // stage next tile into the other buffer (safe: all waves passed barrier)
    if (mt < 15) {
#pragma unroll
      for (int t = 0; t < 2; ++t) {
        const int i = tid + t * 256;
        const int row = i >> 3, ch = i & 7;
        const int p = row * 64 + ((ch ^ (row & 7)) * 8);
        *(us8*)&Kb[(mt + 1) & 1][p] = kr[t];
        *(us8*)&Vb[(mt + 1) & 1][p] = vr[t];
      }
    }
  }

  // row sums (reduce over g), then per-O-row inverse
#pragma unroll
  for (int grp = 0; grp < 2; ++grp) {
    lsum[grp] += __shfl_xor(lsum[grp], 16);
    lsum[grp] += __shfl_xor(lsum[grp], 32);
  }
  float linv[2][4];
#pragma unroll
  for (int grp = 0; grp < 2; ++grp)
#pragma unroll
    for (int r = 0; r < 4; ++r)
      linv[grp][r] = 1.0f / __shfl(lsum[grp], 4 * g + r);

  float ssum = 0.f, ssq = 0.f;
#pragma unroll
  for (int grp = 0; grp < 2; ++grp)
#pragma unroll
    for (int f = 0; f < 4; ++f)
#pragma unroll
      for (int r = 0; r < 4; ++r) {
        const float v = O[grp][f][r] * linv[grp][r];
        ssum += v;
        ssq = fmaf(v, v, ssq);
        Ps[(rb + 16 * grp + 4 * g + r) * 72 + 16 * f + c] = f2bf(v);  // Out[row][d]
      }
#pragma unroll
  for (int off = 1; off < 64; off <<= 1) {
    ssum += __shfl_xor(ssum, off);
    ssq  += __shfl_xor(ssq, off);
  }
  if (lane == 0) {
    atomicAdd(&stats[b * 2 + 0], ssum);
    atomicAdd(&stats[b * 2 + 1], ssq);
  }

  __syncthreads();
  unsigned short* dst = xpfT + ((size_t)b * 1024 + n0) * 512 + pOut * 256 + head * 64;
#pragma unroll
  for (int t = 0; t < 4; ++t) {
    const int i = tid + t * 256;
    const int row = i >> 3, ch = i & 7;
    *(us8*)(dst + (size_t)row * 512 + ch * 8) = *(const us8*)&Ps[row * 72 + ch * 8];
  }
}

// ---------------------------------------------------------------------------
// LayerNorm apply: xln[b][tok][512] = (xpfT - mean)*rstd*gammaT + betaT (bf16)
// ---------------------------------------------------------------------------
__global__ __launch_bounds__(256)
void ln_k(const unsigned short* __restrict__ xpfT, const unsigned short* __restrict__ gbT,
          const float* __restrict__ stats, unsigned short* __restrict__ xln)
{
  const int i = blockIdx.x * 256 + threadIdx.x;   // us8 chunk index, 524288 total
  const int b = i >> 16, off = i & 65535;
  const float invN = 1.0f / 524288.0f;
  const float mean = stats[b * 2] * invN;
  const float var = stats[b * 2 + 1] * invN - mean * mean;
  const float rstd = rsqrtf(var + 1e-5f);
  const us8 xv = *(const us8*)(xpfT + (size_t)i * 8);
  const us8 gv = *(const us8*)(gbT + (size_t)off * 8);
  const us8 bv = *(const us8*)(gbT + 524288 + (size_t)off * 8);
  us8 ov;
#pragma unroll
  for (int j = 0; j < 8; ++j)
    ov[j] = f2bf((bf2f(xv[j]) - mean) * rstd * bf2f(gv[j]) + bf2f(bv[j]));
  *(us8*)(xln + (size_t)i * 8) = ov;
}

// ---------------------------------------------------------------------------
extern "C" void kernel_launch(void* const* d_in, const int* in_sizes, int n_in,
                              void* d_out, int out_size, void* d_ws, size_t ws_size,
                              hipStream_t stream)
{
  const float* x     = (const float*)d_in[0];
  const float* qkvfw = (const float*)d_in[1];
  const float* qkvpw = (const float*)d_in[2];
  const float* hrel  = (const float*)d_in[3];
  const float* wrel  = (const float*)d_in[4];
  const float* gamma = (const float*)d_in[5];
  const float* beta  = (const float*)d_in[6];
  const float* fc1w  = (const float*)d_in[7];
  const float* fc1b  = (const float*)d_in[8];
  const float* fc2w  = (const float*)d_in[9];
  const float* fc2b  = (const float*)d_in[10];
  float* out = (float*)d_out;

  // ws layout (bf16 elements unless noted), ~63.4 MB total
  float* stats = (float*)d_ws;                                   // 64 f32
  unsigned short* wc   = (unsigned short*)(stats + 64);          // 1179648
  unsigned short* xT   = wc + 1179648;                           // 4194304 (reused as xln)
  unsigned short* gbT  = xT + 4194304;                           // 1048576
  unsigned short* qkT  = gbT + 1048576;                          // 8388608
  unsigned short* vbuf = qkT + 8388608;                          // 4194304
  unsigned short* xpfT = vbuf + 4194304;                         // 4194304
  unsigned short* hT   = xpfT + 4194304;                         // 8388608

  hipMemsetAsync(stats, 0, 64 * sizeof(float), stream);

  prep_k<<<2432, 256, 0, stream>>>(qkvfw, qkvpw, fc1w, fc2w, wc,
                                   x, xT, gamma, beta, gbT);

  gemm_mf<0, 256, 128><<<dim3(6, 16, 16), 256, 0, stream>>>(
      wc, xT, qkT, vbuf, nullptr, nullptr, nullptr);

  attn_k<<<dim3(64, 8), 256, 0, stream>>>(qkT, vbuf, hrel, wrel, xpfT, stats);

  ln_k<<<2048, 256, 0, stream>>>(xpfT, gbT, stats, xT);   // xT reused as xln

  gemm_mf<1, 512, 128><<<dim3(8, 16, 8), 256, 0, stream>>>(
      wc + 393216, xT, nullptr, nullptr, hT, nullptr, fc1b);

  gemm_mf<2, 1024, 64><<<dim3(4, 16, 8), 256, 0, stream>>>(
      wc + 917504, hT, nullptr, nullptr, nullptr, out, fc2b);
}

// Round 15
// 226.951 us; speedup vs baseline: 1.0216x; 1.0216x over previous
//
#include <hip/hip_runtime.h>

#define SCALE 0.125f

typedef short short8 __attribute__((ext_vector_type(8)));
typedef float f32x4 __attribute__((ext_vector_type(4)));
typedef unsigned short us8 __attribute__((ext_vector_type(8)));

__device__ __forceinline__ unsigned short f2bf(float x) {
  unsigned int u = __float_as_uint(x);
  u += 0x7fff + ((u >> 16) & 1);
  return (unsigned short)(u >> 16);
}
__device__ __forceinline__ float bf2f(unsigned short b) {
  return __uint_as_float(((unsigned int)b) << 16);
}
__device__ __forceinline__ float gelu_exact(float x) {
  return 0.5f * x * (1.0f + erff(x * 0.70710678118654752f));
}
// async global -> LDS DMA, 16 B per lane; lds base must be wave-uniform,
// lane i lands at lds + i*16. Tracked by vmcnt (drained by __syncthreads).
__device__ __forceinline__ void gl2lds16(const unsigned short* g, unsigned short* l) {
  __builtin_amdgcn_global_load_lds(
      (const __attribute__((address_space(1))) unsigned int*)g,
      (__attribute__((address_space(3))) unsigned int*)l, 16, 0, 0);
}

// ---------------------------------------------------------------------------
// Fused preprocessing: one launch, range-branched.
//   bid <  1152           : cast_w  (qkvf|qkvp|fc1w|fc2w -> wc bf16)
//   bid <  1152+1024      : trans_x (x -> xT transposed bf16)
//   else (256 blocks)     : trans_gb(gamma/beta -> gbT transposed bf16)
// ---------------------------------------------------------------------------
__global__ __launch_bounds__(256)
void prep_k(const float* __restrict__ qf, const float* __restrict__ qp,
            const float* __restrict__ f1, const float* __restrict__ f2,
            unsigned short* __restrict__ wc,
            const float* __restrict__ x, unsigned short* __restrict__ xT,
            const float* __restrict__ gamma, const float* __restrict__ beta,
            unsigned short* __restrict__ gbT)
{
  __shared__ unsigned short L[64 * 72];
  const int bid = blockIdx.x;
  if (bid < 1152) {
    const int i4 = (bid * 256 + threadIdx.x) * 4;   // 1179648 total elems
    const float* src; int off;
    if (i4 < 196608)      { src = qf; off = i4; }
    else if (i4 < 393216) { src = qp; off = i4 - 196608; }
    else if (i4 < 917504) { src = f1; off = i4 - 393216; }
    else                  { src = f2; off = i4 - 917504; }
    const float4 v = *(const float4*)(src + off);
    ushort4 o;
    o.x = f2bf(v.x); o.y = f2bf(v.y); o.z = f2bf(v.z); o.w = f2bf(v.w);
    *(ushort4*)(wc + i4) = o;
    return;
  }
  if (bid < 1152 + 1024) {
    const int idx = bid - 1152;                     // (4,16,16) flattened
    const int ch0 = (idx & 3) * 64, tok0 = ((idx >> 2) & 15) * 64, z = idx >> 6;
    const int b = z & 7, path = z >> 3;
    const float* src = x + (size_t)b * 524288 + (size_t)(path * 256 + ch0) * 1024 + tok0;
#pragma unroll
    for (int t = 0; t < 4; ++t) {
      const int i = threadIdx.x + t * 256;
      const int row = i >> 4, c4 = (i & 15) * 4;    // row = ch, c4 = tok
      const float4 v = *(const float4*)(src + (size_t)row * 1024 + c4);
      L[(c4 + 0) * 72 + row] = f2bf(v.x);
      L[(c4 + 1) * 72 + row] = f2bf(v.y);
      L[(c4 + 2) * 72 + row] = f2bf(v.z);
      L[(c4 + 3) * 72 + row] = f2bf(v.w);
    }
    __syncthreads();
    unsigned short* dst = xT + (size_t)z * 262144 + (size_t)tok0 * 256 + ch0;
#pragma unroll
    for (int t = 0; t < 2; ++t) {
      const int i = threadIdx.x + t * 256;
      const int row = i >> 3, c8 = (i & 7) * 8;     // row = tok, c8 = ch
      *(us8*)(dst + (size_t)row * 256 + c8) = *(const us8*)&L[row * 72 + c8];
    }
    return;
  }
  {
    const int idx = bid - 2176;                     // (8,16,2) flattened
    const int ch0 = (idx & 7) * 64, tok0 = ((idx >> 3) & 15) * 64, which = idx >> 7;
    const float* src = (which ? beta : gamma) + (size_t)ch0 * 1024 + tok0;
#pragma unroll
    for (int t = 0; t < 4; ++t) {
      const int i = threadIdx.x + t * 256;
      const int row = i >> 4, c4 = (i & 15) * 4;
      const float4 v = *(const float4*)(src + (size_t)row * 1024 + c4);
      L[(c4 + 0) * 72 + row] = f2bf(v.x);
      L[(c4 + 1) * 72 + row] = f2bf(v.y);
      L[(c4 + 2) * 72 + row] = f2bf(v.z);
      L[(c4 + 3) * 72 + row] = f2bf(v.w);
    }
    __syncthreads();
    unsigned short* dst = gbT + (size_t)which * 524288 + (size_t)tok0 * 512 + ch0;
#pragma unroll
    for (int t = 0; t < 2; ++t) {
      const int i = threadIdx.x + t * 256;
      const int row = i >> 3, c8 = (i & 7) * 8;
      *(us8*)(dst + (size_t)row * 512 + c8) = *(const us8*)&L[row * 72 + c8];
    }
  }
}

// ---------------------------------------------------------------------------
// MFMA GEMM v6 (R13-proven): C[M][N] = A[M][K] @ B[N][K]^T, bf16.
// BM x 64 block tile, 4 waves (2x2), BK=64 K-steps. global_load_lds DMA
// staging (T3 ordering, pre-XOR'd source swizzle q^(row&7), 1 barrier/step).
// LDS-transpose epilogues (R12-proven, -12.7us): coalesced 16B stores.
// MODE 0: qkv -> qkT[z][tok][512] (m<512, transposed) + vbuf[z][ch][tok]
// MODE 1: fc1 -> bias+gelu -> hT[z][tok][1024] bf16 (transposed)
// MODE 2: fc2 -> bias -> out[z][oc][tok] f32
// ---------------------------------------------------------------------------
template<int MODE, int K, int BM>
__global__ __launch_bounds__(256, 3)
void gemm_mf(const unsigned short* __restrict__ A0, const unsigned short* __restrict__ B0,
             unsigned short* __restrict__ qkT, unsigned short* __restrict__ vb,
             unsigned short* __restrict__ hT, float* __restrict__ outF,
             const float* __restrict__ bias)
{
  constexpr int BN = 64;
  constexpr int MI = BM / 32;                 // fragments per wave in M
  constexpr int NI = BN / 32;                 // = 2
  constexpr int ABUF = BM * 64;               // shorts per A buffer
  constexpr int BBUF = BN * 64;               // shorts per B buffer
  constexpr int STG_A = 2 * ABUF;
  constexpr int STG = STG_A + 2 * BBUF;
  constexpr int USZ = (STG > 9216) ? STG : 9216;  // epilogue needs <= 9216
  __shared__ __align__(16) unsigned short U[USZ];
  const int tid = threadIdx.x;
  const int lane = tid & 63, w = tid >> 6;
  const int c = lane & 15, g = lane >> 4;
  const int wm = w >> 1, wn = w & 1;
  const int m0 = blockIdx.x * BM, n0 = blockIdx.y * BN;
  const int z = blockIdx.z;

  const unsigned short* A;
  const unsigned short* B;
  if (MODE == 0) {
    A = A0 + (size_t)(z >> 3) * 196608;
    B = B0 + (size_t)z * 262144;
  } else {
    A = A0;
    B = B0 + (size_t)z * 1024 * K;
  }

  f32x4 acc[MI][NI];
#pragma unroll
  for (int mi = 0; mi < MI; ++mi)
#pragma unroll
    for (int ni = 0; ni < NI; ++ni) acc[mi][ni] = (f32x4){0.f, 0.f, 0.f, 0.f};

  // DMA geometry (BK=64): rows are 64 shorts = 8 chunks of 8. One call
  // covers 8 rows (64 lanes x 8 shorts). Lane l -> row = base + (l>>3),
  // chunk q = l&7, source chunk pre-XOR'd (q ^ (row&7)); (row&7) is
  // invariant under the +8 call stride, so one sc8 serves all calls.
  const int r0a = (BM == 128) ? (w * 32 + (lane >> 3)) : (w * 16 + (lane >> 3));
  const int sc8a = ((lane & 7) ^ (r0a & 7)) * 8;
  const int loa = (BM == 128) ? (w * 2048) : (w * 1024);
  const int r0b = w * 16 + (lane >> 3);       // B: 64 rows, 2 calls/wave
  const int sc8b = ((lane & 7) ^ (r0b & 7)) * 8;
  const int lob = w * 1024;

  // prologue: DMA tile 0 into buf 0
  gl2lds16(A + (size_t)(m0 + r0a) * K + sc8a,      &U[loa]);
  gl2lds16(A + (size_t)(m0 + r0a + 8) * K + sc8a,  &U[loa + 512]);
  if (BM == 128) {
    gl2lds16(A + (size_t)(m0 + r0a + 16) * K + sc8a, &U[loa + 1024]);
    gl2lds16(A + (size_t)(m0 + r0a + 24) * K + sc8a, &U[loa + 1536]);
  }
  gl2lds16(B + (size_t)(n0 + r0b) * K + sc8b,      &U[STG_A + lob]);
  gl2lds16(B + (size_t)(n0 + r0b + 8) * K + sc8b,  &U[STG_A + lob + 512]);
  __syncthreads();   // drain tile-0 DMA

  const int NK = K / 64;
  for (int ks = 0; ks < NK; ++ks) {
    const int buf = ks & 1;
    if (ks + 1 < NK) {
      const int k0 = (ks + 1) * 64;
      const int nb = buf ^ 1;
      gl2lds16(A + (size_t)(m0 + r0a) * K + k0 + sc8a,      &U[nb * ABUF + loa]);
      gl2lds16(A + (size_t)(m0 + r0a + 8) * K + k0 + sc8a,  &U[nb * ABUF + loa + 512]);
      if (BM == 128) {
        gl2lds16(A + (size_t)(m0 + r0a + 16) * K + k0 + sc8a, &U[nb * ABUF + loa + 1024]);
        gl2lds16(A + (size_t)(m0 + r0a + 24) * K + k0 + sc8a, &U[nb * ABUF + loa + 1536]);
      }
      gl2lds16(B + (size_t)(n0 + r0b) * K + k0 + sc8b,      &U[STG_A + nb * BBUF + lob]);
      gl2lds16(B + (size_t)(n0 + r0b + 8) * K + k0 + sc8b,  &U[STG_A + nb * BBUF + lob + 512]);
    }
    // fragments: k-half h chunk = 4h+g, stored at chunk (4h+g)^(row&7)
    short8 aF[MI][2], bF[NI][2];
#pragma unroll
    for (int mi = 0; mi < MI; ++mi) {
      const int row = (BM / 2) * wm + 16 * mi + c;
      const int base = buf * ABUF + row * 64;
      aF[mi][0] = *(const short8*)&U[base + ((g ^ (row & 7)) * 8)];
      aF[mi][1] = *(const short8*)&U[base + (((4 + g) ^ (row & 7)) * 8)];
    }
#pragma unroll
    for (int ni = 0; ni < NI; ++ni) {
      const int row = 32 * wn + 16 * ni + c;
      const int base = STG_A + buf * BBUF + row * 64;
      bF[ni][0] = *(const short8*)&U[base + ((g ^ (row & 7)) * 8)];
      bF[ni][1] = *(const short8*)&U[base + (((4 + g) ^ (row & 7)) * 8)];
    }
#pragma unroll
    for (int mi = 0; mi < MI; ++mi)
#pragma unroll
      for (int ni = 0; ni < NI; ++ni) {
        acc[mi][ni] = __builtin_amdgcn_mfma_f32_16x16x32_bf16(aF[mi][0], bF[ni][0], acc[mi][ni], 0, 0, 0);
        acc[mi][ni] = __builtin_amdgcn_mfma_f32_16x16x32_bf16(aF[mi][1], bF[ni][1], acc[mi][ni], 0, 0, 0);
      }
    // single end-of-iteration barrier: vmcnt(0) drain lands after the full
    // compute phase, so the tile-(ks+1) DMA latency is hidden.
    __syncthreads();
  }
  // (final barrier above also makes U safe to reuse for the epilogue)

  if (MODE == 0) {
    if (m0 < 512) {
      // qkT[z][n][512]: LDS tile [64 n][BM mb], row stride 136; single pass.
#pragma unroll
      for (int mi = 0; mi < MI; ++mi)
#pragma unroll
        for (int ni = 0; ni < NI; ++ni) {
          const int row = 32 * wn + 16 * ni + c;
          const int col = (BM / 2) * wm + 16 * mi + 4 * g;
          ushort4 o4;
          o4.x = f2bf(acc[mi][ni][0]); o4.y = f2bf(acc[mi][ni][1]);
          o4.z = f2bf(acc[mi][ni][2]); o4.w = f2bf(acc[mi][ni][3]);
          *(ushort4*)&U[row * 136 + col] = o4;
        }
      __syncthreads();
#pragma unroll
      for (int t = 0; t < 4; ++t) {
        const int i = tid + t * 256;
        const int row = i >> 4, c8 = (i & 15) * 8;
        *(us8*)(qkT + (size_t)z * 524288 + (size_t)(n0 + row) * 512 + m0 + c8)
            = *(const us8*)&U[row * 136 + c8];
      }
    } else {
      // vbuf[z][ch][1024]: LDS tile [BM ch][64 n], row stride 72; single pass.
#pragma unroll
      for (int mi = 0; mi < MI; ++mi)
#pragma unroll
        for (int ni = 0; ni < NI; ++ni) {
          const int mbl = (BM / 2) * wm + 16 * mi + 4 * g;
          const int nl = 32 * wn + 16 * ni + c;
#pragma unroll
          for (int r = 0; r < 4; ++r)
            U[(mbl + r) * 72 + nl] = f2bf(acc[mi][ni][r]);
        }
      __syncthreads();
#pragma unroll
      for (int t = 0; t < 4; ++t) {
        const int i = tid + t * 256;
        const int row = i >> 3, c8 = (i & 7) * 8;
        *(us8*)(vb + (size_t)z * 262144 + (size_t)(m0 - 512 + row) * 1024 + n0 + c8)
            = *(const us8*)&U[row * 72 + c8];
      }
    }
  } else if (MODE == 1) {
    // hT[z][tok][1024]: LDS tile [64 n][BM mb], row stride 136; single pass.
#pragma unroll
    for (int mi = 0; mi < MI; ++mi) {
      const int mb = m0 + (BM / 2) * wm + 16 * mi + 4 * g;
      const float4 b4 = *(const float4*)(bias + mb);
#pragma unroll
      for (int ni = 0; ni < NI; ++ni) {
        const int row = 32 * wn + 16 * ni + c;
        const int col = (BM / 2) * wm + 16 * mi + 4 * g;
        ushort4 o4;
        o4.x = f2bf(gelu_exact(acc[mi][ni][0] + b4.x));
        o4.y = f2bf(gelu_exact(acc[mi][ni][1] + b4.y));
        o4.z = f2bf(gelu_exact(acc[mi][ni][2] + b4.z));
        o4.w = f2bf(gelu_exact(acc[mi][ni][3] + b4.w));
        *(ushort4*)&U[row * 136 + col] = o4;
      }
    }
    __syncthreads();
#pragma unroll
    for (int t = 0; t < 4; ++t) {
      const int i = tid + t * 256;
      const int row = i >> 4, c8 = (i & 15) * 8;
      *(us8*)(hT + (size_t)z * 1048576 + (size_t)(n0 + row) * 1024 + m0 + c8)
          = *(const us8*)&U[row * 136 + c8];
    }
  } else {
    // out[z][oc][1024] f32: LDS tile [BM=64 oc][64 n] f32, stride 68; 1 pass.
    float* Uf = (float*)U;
#pragma unroll
    for (int mi = 0; mi < MI; ++mi) {
      const int mb = m0 + (BM / 2) * wm + 16 * mi + 4 * g;
      const float4 b4 = *(const float4*)(bias + mb);
#pragma unroll
      for (int ni = 0; ni < NI; ++ni) {
        const int mbl = (BM / 2) * wm + 16 * mi + 4 * g;
        const int nl = 32 * wn + 16 * ni + c;
        Uf[(mbl + 0) * 68 + nl] = acc[mi][ni][0] + b4.x;
        Uf[(mbl + 1) * 68 + nl] = acc[mi][ni][1] + b4.y;
        Uf[(mbl + 2) * 68 + nl] = acc[mi][ni][2] + b4.z;
        Uf[(mbl + 3) * 68 + nl] = acc[mi][ni][3] + b4.w;
      }
    }
    __syncthreads();
#pragma unroll
    for (int t = 0; t < 4; ++t) {
      const int i = tid + t * 256;
      const int row = i >> 4, c4 = (i & 15) * 4;
      *(float4*)(outF + (size_t)z * 262144 + (size_t)(m0 + row) * 1024 + n0 + c4)
          = *(const float4*)&Uf[row * 68 + c4];
    }
  }
}

// ---------------------------------------------------------------------------
// MFMA flash attention v3 (R0/R8/R12/R13-proven, ~87us best-container):
// FROZEN. Block = 128 q-rows of one (path,b,head); 4 waves x 32 q-rows.
// S computed transposed (A=K, B=Q); P via LDS b64 packs; K/V double-buffered,
// 1 barrier/iter, next tile prefetched into registers. XOR-swizzled tiles.
// Seven probes falsified: occupancy (v5/v9), DMA staging (v6), P-in-reg
// (v8), barrier-free direct-cache (v10), exp2 fold (R14: VGPR 100->104,
// schedule perturbed, net regression).
// ---------------------------------------------------------------------------
__global__ __launch_bounds__(256, 2)
void attn_k(const unsigned short* __restrict__ qkT,  // [16][1024][512] bf16
            const unsigned short* __restrict__ vbuf, // [16][256][1024] bf16
            const float* __restrict__ hrel,          // [63][64] f32
            const float* __restrict__ wrel,          // [63][64] f32
            unsigned short* __restrict__ xpfT,       // [8][1024][512] bf16
            float* __restrict__ stats)               // [8][2] f32
{
  __shared__ unsigned short Kb[2][4096];   // K tile [key][d], swizzled
  __shared__ unsigned short Vb[2][4096];   // V tile [d][key], swizzled
  __shared__ unsigned short Ps[128 * 72];  // QW table / P tile / Out stage
  __shared__ unsigned short QHt[128 * 34]; // qh[row][h2], h2 in [0,32)

  const int tid = threadIdx.x;
  const int lane = tid & 63, w = tid >> 6;
  const int c = lane & 15, g = lane >> 4;
  const int xb = blockIdx.x;
  const int pOut = xb >> 5, bh = xb & 31;
  const int b = bh >> 2, head = bh & 3, pKV = 1 - pOut;
  const int n0 = blockIdx.y * 128;
  const int rb = 32 * w;

  const unsigned short* Qg = qkT + (size_t)(pOut * 8 + b) * 524288 + head * 64;
  const unsigned short* Kg = qkT + (size_t)(pKV * 8 + b) * 524288 + 256 + head * 64;
  const unsigned short* Vg = vbuf + ((size_t)(pKV * 8 + b) * 256 + head * 64) * 1024;

  // ---- issue tile-0 staging loads first (latency hidden behind prologue)
  us8 kr[2], vr[2];
#pragma unroll
  for (int t = 0; t < 2; ++t) {
    const int i = tid + t * 256;
    const int row = i >> 3, ch = i & 7;
    kr[t] = *(const us8*)(Kg + (size_t)row * 512 + ch * 8);
    vr[t] = *(const us8*)(Vg + (size_t)row * 1024 + ch * 8);
  }

  // ---- Q B-fragments for the wave's 2 row-groups (resident all kernel)
  short8 bQ[2][2];
#pragma unroll
  for (int grp = 0; grp < 2; ++grp) {
    const unsigned short* qp = Qg + (size_t)(n0 + rb + 16 * grp + c) * 512 + 8 * g;
    bQ[grp][0] = *(const short8*)(qp);
    bQ[grp][1] = *(const short8*)(qp + 32);
  }

  // ---- prologue: QW/QH via MFMA (A=rel rows, B=Q). Wave-private LDS rows.
#pragma unroll
  for (int f = 0; f < 4; ++f) {
    const int rr = 16 * f + c;
    const int rrc = rr < 63 ? rr : 62;
    const float sc = rr < 63 ? 1.f : 0.f;
    short8 w0, w1, h0, h1;
#pragma unroll
    for (int j = 0; j < 8; ++j) {
      w0[j] = f2bf(wrel[rrc * 64 + 8 * g + j] * sc);
      w1[j] = f2bf(wrel[rrc * 64 + 32 + 8 * g + j] * sc);
      h0[j] = f2bf(hrel[rrc * 64 + 8 * g + j] * sc);
      h1[j] = f2bf(hrel[rrc * 64 + 32 + 8 * g + j] * sc);
    }
#pragma unroll
    for (int grp = 0; grp < 2; ++grp) {
      f32x4 zw = {0.f, 0.f, 0.f, 0.f};
      zw = __builtin_amdgcn_mfma_f32_16x16x32_bf16(w0, bQ[grp][0], zw, 0, 0, 0);
      zw = __builtin_amdgcn_mfma_f32_16x16x32_bf16(w1, bQ[grp][1], zw, 0, 0, 0);
      f32x4 zh = {0.f, 0.f, 0.f, 0.f};
      zh = __builtin_amdgcn_mfma_f32_16x16x32_bf16(h0, bQ[grp][0], zh, 0, 0, 0);
      zh = __builtin_amdgcn_mfma_f32_16x16x32_bf16(h1, bQ[grp][1], zh, 0, 0, 0);
      const int qrow = rb + 16 * grp + c;          // lane's own q-row
      ushort4 pw;
      pw.x = f2bf(zw[0]); pw.y = f2bf(zw[1]); pw.z = f2bf(zw[2]); pw.w = f2bf(zw[3]);
      *(ushort4*)&Ps[qrow * 72 + 16 * f + 4 * g] = pw;   // QW[qrow][rw]
      const int h1i = (n0 + qrow) >> 5;
#pragma unroll
      for (int r = 0; r < 4; ++r) {
        const int h2 = 16 * f + 4 * g + r - 31 + h1i;
        if (h2 >= 0 && h2 < 32) QHt[qrow * 34 + h2] = f2bf(zh[r]);
      }
    }
  }

  // read back the 16 loop-invariant qw values (wave-private rows, in-order LDS)
  float qwv[2][2][4];
#pragma unroll
  for (int grp = 0; grp < 2; ++grp) {
    const int qrow = rb + 16 * grp + c;
    const int w1i = (n0 + qrow) & 31;
#pragma unroll
    for (int p = 0; p < 2; ++p)
#pragma unroll
      for (int r = 0; r < 4; ++r)
        qwv[grp][p][r] = bf2f(Ps[qrow * 72 + (16 * p + 4 * g + r - w1i + 31)]);
  }

  // write tile 0 to buffer 0
#pragma unroll
  for (int t = 0; t < 2; ++t) {
    const int i = tid + t * 256;
    const int row = i >> 3, ch = i & 7;
    const int p = row * 64 + ((ch ^ (row & 7)) * 8);
    *(us8*)&Kb[0][p] = kr[t];
    *(us8*)&Vb[0][p] = vr[t];
  }

  float lsum[2] = {0.f, 0.f};
  f32x4 O[2][4];
#pragma unroll
  for (int grp = 0; grp < 2; ++grp)
#pragma unroll
    for (int f = 0; f < 4; ++f) O[grp][f] = (f32x4){0.f, 0.f, 0.f, 0.f};

  for (int mt = 0; mt < 16; ++mt) {
    if (mt < 15) {
      const int m0n = (mt + 1) * 64;
#pragma unroll
      for (int t = 0; t < 2; ++t) {
        const int i = tid + t * 256;
        const int row = i >> 3, ch = i & 7;
        kr[t] = *(const us8*)(Kg + (size_t)(m0n + row) * 512 + ch * 8);
        vr[t] = *(const us8*)(Vg + (size_t)row * 1024 + m0n + ch * 8);
      }
    }
    __syncthreads();   // current buffer staged & all prior-tile reads done
    const unsigned short* Ks = Kb[mt & 1];
    const unsigned short* Vs = Vb[mt & 1];

    // K fragments (shared by both q-groups)
    short8 kA[4][2];
#pragma unroll
    for (int f = 0; f < 4; ++f) {
      const int row = 16 * f + c;
      kA[f][0] = *(const short8*)&Ks[row * 64 + ((g ^ (row & 7)) * 8)];
      kA[f][1] = *(const short8*)&Ks[row * 64 + (((4 + g) ^ (row & 7)) * 8)];
    }
    // S^T = K Q^T, softmax, P -> LDS (wave-private rows, b64 packs)
#pragma unroll
    for (int grp = 0; grp < 2; ++grp) {
      const int qrow = rb + 16 * grp + c;
      const float qh0 = bf2f(QHt[qrow * 34 + 2 * mt]);
      const float qh1 = bf2f(QHt[qrow * 34 + 2 * mt + 1]);
#pragma unroll
      for (int f = 0; f < 4; ++f) {
        f32x4 z = {0.f, 0.f, 0.f, 0.f};
        z = __builtin_amdgcn_mfma_f32_16x16x32_bf16(kA[f][0], bQ[grp][0], z, 0, 0, 0);
        z = __builtin_amdgcn_mfma_f32_16x16x32_bf16(kA[f][1], bQ[grp][1], z, 0, 0, 0);
        const float qh = (f >= 2) ? qh1 : qh0;
        const float* qwp = qwv[grp][f & 1];
        const float p0 = __expf(fmaf(z[0], SCALE, qh + qwp[0]));
        const float p1 = __expf(fmaf(z[1], SCALE, qh + qwp[1]));
        const float p2 = __expf(fmaf(z[2], SCALE, qh + qwp[2]));
        const float p3 = __expf(fmaf(z[3], SCALE, qh + qwp[3]));
        lsum[grp] += (p0 + p1) + (p2 + p3);
        ushort4 pk;
        pk.x = f2bf(p0); pk.y = f2bf(p1); pk.z = f2bf(p2); pk.w = f2bf(p3);
        *(ushort4*)&Ps[qrow * 72 + 16 * f + 4 * g] = pk;
      }
    }
    // V fragments (shared by both q-groups)
    short8 vB[4][2];
#pragma unroll
    for (int f = 0; f < 4; ++f) {
      const int row = 16 * f + c;
      vB[f][0] = *(const short8*)&Vs[row * 64 + ((g ^ (row & 7)) * 8)];
      vB[f][1] = *(const short8*)&Vs[row * 64 + (((4 + g) ^ (row & 7)) * 8)];
    }
    // O += P V  (A=P from wave-private LDS rows, in-wave ordering)
#pragma unroll
    for (int grp = 0; grp < 2; ++grp) {
      const int qrow = rb + 16 * grp + c;
      const short8 aP0 = *(const short8*)&Ps[qrow * 72 + 8 * g];
      const short8 aP1 = *(const short8*)&Ps[qrow * 72 + 32 + 8 * g];
#pragma unroll
      for (int f = 0; f < 4; ++f) {
        O[grp][f] = __builtin_amdgcn_mfma_f32_16x16x32_bf16(aP0, vB[f][0], O[grp][f], 0, 0, 0);
        O[grp][f] = __builtin_amdgcn_mfma_f32_16x16x32_bf16(aP1, vB[f][1], O[grp][f], 0, 0, 0);
      }
    }
    // stage next tile into the other buffer (safe: all waves passed barrier)
    if (mt < 15) {
#pragma unroll
      for (int t = 0; t < 2; ++t) {
        const int i = tid + t * 256;
        const int row = i >> 3, ch = i & 7;
        const int p = row * 64 + ((ch ^ (row & 7)) * 8);
        *(us8*)&Kb[(mt + 1) & 1][p] = kr[t];
        *(us8*)&Vb[(mt + 1) & 1][p] = vr[t];
      }
    }
  }

  // row sums (reduce over g), then per-O-row inverse
#pragma unroll
  for (int grp = 0; grp < 2; ++grp) {
    lsum[grp] += __shfl_xor(lsum[grp], 16);
    lsum[grp] += __shfl_xor(lsum[grp], 32);
  }
  float linv[2][4];
#pragma unroll
  for (int grp = 0; grp < 2; ++grp)
#pragma unroll
    for (int r = 0; r < 4; ++r)
      linv[grp][r] = 1.0f / __shfl(lsum[grp], 4 * g + r);

  float ssum = 0.f, ssq = 0.f;
#pragma unroll
  for (int grp = 0; grp < 2; ++grp)
#pragma unroll
    for (int f = 0; f < 4; ++f)
#pragma unroll
      for (int r = 0; r < 4; ++r) {
        const float v = O[grp][f][r] * linv[grp][r];
        ssum += v;
        ssq = fmaf(v, v, ssq);
        Ps[(rb + 16 * grp + 4 * g + r) * 72 + 16 * f + c] = f2bf(v);  // Out[row][d]
      }
#pragma unroll
  for (int off = 1; off < 64; off <<= 1) {
    ssum += __shfl_xor(ssum, off);
    ssq  += __shfl_xor(ssq, off);
  }
  if (lane == 0) {
    atomicAdd(&stats[b * 2 + 0], ssum);
    atomicAdd(&stats[b * 2 + 1], ssq);
  }

  __syncthreads();
  unsigned short* dst = xpfT + ((size_t)b * 1024 + n0) * 512 + pOut * 256 + head * 64;
#pragma unroll
  for (int t = 0; t < 4; ++t) {
    const int i = tid + t * 256;
    const int row = i >> 3, ch = i & 7;
    *(us8*)(dst + (size_t)row * 512 + ch * 8) = *(const us8*)&Ps[row * 72 + ch * 8];
  }
}

// ---------------------------------------------------------------------------
// LayerNorm apply: xln[b][tok][512] = (xpfT - mean)*rstd*gammaT + betaT (bf16)
// ---------------------------------------------------------------------------
__global__ __launch_bounds__(256)
void ln_k(const unsigned short* __restrict__ xpfT, const unsigned short* __restrict__ gbT,
          const float* __restrict__ stats, unsigned short* __restrict__ xln)
{
  const int i = blockIdx.x * 256 + threadIdx.x;   // us8 chunk index, 524288 total
  const int b = i >> 16, off = i & 65535;
  const float invN = 1.0f / 524288.0f;
  const float mean = stats[b * 2] * invN;
  const float var = stats[b * 2 + 1] * invN - mean * mean;
  const float rstd = rsqrtf(var + 1e-5f);
  const us8 xv = *(const us8*)(xpfT + (size_t)i * 8);
  const us8 gv = *(const us8*)(gbT + (size_t)off * 8);
  const us8 bv = *(const us8*)(gbT + 524288 + (size_t)off * 8);
  us8 ov;
#pragma unroll
  for (int j = 0; j < 8; ++j)
    ov[j] = f2bf((bf2f(xv[j]) - mean) * rstd * bf2f(gv[j]) + bf2f(bv[j]));
  *(us8*)(xln + (size_t)i * 8) = ov;
}

// ---------------------------------------------------------------------------
extern "C" void kernel_launch(void* const* d_in, const int* in_sizes, int n_in,
                              void* d_out, int out_size, void* d_ws, size_t ws_size,
                              hipStream_t stream)
{
  const float* x     = (const float*)d_in[0];
  const float* qkvfw = (const float*)d_in[1];
  const float* qkvpw = (const float*)d_in[2];
  const float* hrel  = (const float*)d_in[3];
  const float* wrel  = (const float*)d_in[4];
  const float* gamma = (const float*)d_in[5];
  const float* beta  = (const float*)d_in[6];
  const float* fc1w  = (const float*)d_in[7];
  const float* fc1b  = (const float*)d_in[8];
  const float* fc2w  = (const float*)d_in[9];
  const float* fc2b  = (const float*)d_in[10];
  float* out = (float*)d_out;

  // ws layout (bf16 elements unless noted), ~63.4 MB total
  float* stats = (float*)d_ws;                                   // 64 f32
  unsigned short* wc   = (unsigned short*)(stats + 64);          // 1179648
  unsigned short* xT   = wc + 1179648;                           // 4194304 (reused as xln)
  unsigned short* gbT  = xT + 4194304;                           // 1048576
  unsigned short* qkT  = gbT + 1048576;                          // 8388608
  unsigned short* vbuf = qkT + 8388608;                          // 4194304
  unsigned short* xpfT = vbuf + 4194304;                         // 4194304
  unsigned short* hT   = xpfT + 4194304;                         // 8388608

  hipMemsetAsync(stats, 0, 64 * sizeof(float), stream);

  prep_k<<<2432, 256, 0, stream>>>(qkvfw, qkvpw, fc1w, fc2w, wc,
                                   x, xT, gamma, beta, gbT);

  gemm_mf<0, 256, 128><<<dim3(6, 16, 16), 256, 0, stream>>>(
      wc, xT, qkT, vbuf, nullptr, nullptr, nullptr);

  attn_k<<<dim3(64, 8), 256, 0, stream>>>(qkT, vbuf, hrel, wrel, xpfT, stats);

  ln_k<<<2048, 256, 0, stream>>>(xpfT, gbT, stats, xT);   // xT reused as xln

  gemm_mf<1, 512, 128><<<dim3(8, 16, 8), 256, 0, stream>>>(
      wc + 393216, xT, nullptr, nullptr, hT, nullptr, fc1b);

  gemm_mf<2, 1024, 64><<<dim3(4, 16, 8), 256, 0, stream>>>(
      wc + 917504, hT, nullptr, nullptr, nullptr, out, fc2b);
}